// Round 8
// baseline (669.002 us; speedup 1.0000x reference)
//
#include <hip/hip_runtime.h>
#include <stdint.h>

#define B_  16
#define C_  256
#define HW_ 4096
#define Hp  66
#define PP  4356   // 66*66
#define EPS_ 1e-5f

typedef unsigned short u16;
typedef unsigned int   u32;
typedef __attribute__((ext_vector_type(4))) float  f32x4;
typedef __attribute__((ext_vector_type(8))) __bf16 bf16x8;
typedef __attribute__((ext_vector_type(8))) u16    u16x8;

__device__ __forceinline__ float bf2f(u16 u){ u32 x = ((u32)u)<<16; float f; __builtin_memcpy(&f,&x,4); return f; }
__device__ __forceinline__ u16 f2bf(float f){ u32 x; __builtin_memcpy(&x,&f,4); u32 r = x + 0x7fffu + ((x>>16)&1u); return (u16)(r>>16); }

__device__ __forceinline__ void g2l16(const void* g, void* l){
  __builtin_amdgcn_global_load_lds((__attribute__((address_space(1))) void*)(void*)g,
                                   (__attribute__((address_space(3))) void*)l, 16, 0, 0);
}
__device__ __forceinline__ bf16x8 ldfrag(const u16* p){
  u16x8 r = *(const u16x8*)p;
  return __builtin_bit_cast(bf16x8, r);
}

// ---------------- K0: pad + transpose + cast x -> xpT[b][66*66][256] bf16 ----------------
__global__ __launch_bounds__(256) void k_pad(const float* __restrict__ x, u16* __restrict__ xpT){
  int bid = blockIdx.x; int b = bid/66, hh = bid - b*66; int tid = threadIdx.x;
  u16* rowbase = xpT + (size_t)(b*PP + hh*Hp)*C_;
  if(hh==0 || hh==65){
    u32* p = (u32*)rowbase;
    for(int i=tid;i<66*C_/2;i+=256) p[i]=0u;
    return;
  }
  if(tid<128) ((u32*)rowbase)[tid]=0u;                 // ww = 0 border
  else ((u32*)(rowbase + 65*C_))[tid-128]=0u;          // ww = 65 border
  int h = hh-1;
  __shared__ float Lt[64*65];
  for(int cc=0; cc<4; cc++){
    int c0=cc*64;
    int ci = tid>>2, w0 = (tid&3)*16;
    const float* xs = x + ((size_t)(b*C_ + c0+ci)*HW_) + h*64 + w0;
    for(int j=0;j<4;j++){
      float4 v = *(const float4*)(xs + j*4);
      Lt[ci*65 + w0 + j*4 + 0] = v.x;
      Lt[ci*65 + w0 + j*4 + 1] = v.y;
      Lt[ci*65 + w0 + j*4 + 2] = v.z;
      Lt[ci*65 + w0 + j*4 + 3] = v.w;
    }
    __syncthreads();
    int w = tid>>2, cj = (tid&3)*16;
    union { u16 u[16]; uint4 v[2]; } outu;
    for(int j=0;j<16;j++) outu.u[j] = f2bf(Lt[(cj+j)*65 + w]);
    uint4* dst = (uint4*)(rowbase + (size_t)(w+1)*C_ + c0 + cj);
    dst[0]=outu.v[0]; dst[1]=outu.v[1];
    __syncthreads();
  }
}

// ---------------- K1: repack weights/context to bf16, zero stats ----------------
__global__ __launch_bounds__(256) void k_repack(
    const float* __restrict__ conv_w, const float* __restrict__ wq, const float* __restrict__ wo,
    const float* __restrict__ wk, const float* __restrict__ wv, const float* __restrict__ ctx,
    u16* __restrict__ wBt, u16* __restrict__ wqB, u16* __restrict__ woB,
    u16* __restrict__ wkvB, u16* __restrict__ ctxB, float* __restrict__ stats){
  int i = blockIdx.x*256 + threadIdx.x;
  if(i < 589824){ int co = i/2304, k = i - co*2304; int t = k>>8, ci = k&255;
    wBt[i] = f2bf(conv_w[(co*256+ci)*9 + t]); return; }
  i -= 589824;
  if(i < 65536){ wqB[i] = f2bf(wq[i]); return; } i -= 65536;
  if(i < 65536){ woB[i] = f2bf(wo[i]); return; } i -= 65536;
  if(i < 196608){ wkvB[i] = f2bf(wk[i]); return; } i -= 196608;
  if(i < 196608){ wkvB[196608+i] = f2bf(wv[i]); return; } i -= 196608;
  if(i < 946176){ ctxB[i] = f2bf(ctx[i]); return; } i -= 946176;
  if(i < 512){ stats[i] = 0.f; }
}

// ---------------- K2: conv implicit GEMM — reg-staged, 72B-padded LDS, 1-barrier pipeline -
// LDS rows padded to 36 u16 (72 B): frag-read banks (ln*18)%32 all-distinct -> conflict-free.
// Pipeline invariant at tap s: Bs[cb]=B(s), rb=B(s+1). Body: ds_write rb->Bs[cb^1];
// issue rb=load B(s+2); compute s from Bs[cb]; barrier (vmcnt drain lands AFTER compute).
__global__ __launch_bounds__(256, 2) void k_conv(const u16* __restrict__ xpT, const u16* __restrict__ wBt,
    const float* __restrict__ conv_b, u16* __restrict__ h, float* __restrict__ stats){
  __shared__ u16 As[264*36];       // 19008 B
  __shared__ u16 Bs[2][256*36];    // 2 x 18432 B
  int bid = blockIdx.x;
  int b = bid >> 5, hp = bid & 31;
  int tid = threadIdx.x;
  int w = tid>>6, lane = tid&63, ln = lane&15, qd = lane>>4;
  int wm = w&1, wn = w>>1;
  const u16* Abase = xpT + (size_t)(b*PP + hp*132)*C_;
  f32x4 acc[4][8] = {};
  int hr_[4], wp_[4];
  #pragma unroll
  for(int mf=0;mf<4;mf++){ int p = wm*64 + mf*16 + ln; hr_[mf] = p>>6; wp_[mf] = p&63; }
  // B staging constants: chunk c = r*256+tid -> co=c>>2, atom=c&3
  const u16* bsrc[4]; int bofs[4];
  #pragma unroll
  for(int r=0;r<4;r++){
    int c = r*256 + tid; int co = c>>2, at = c&3;
    bsrc[r] = wBt + (size_t)co*2304 + at*8;
    bofs[r] = co*36 + at*8;
  }
  // A staging constants: chunk c = r*256+tid (c<1056) -> row=c>>2, atom=c&3
  const u16* asrc[5]; int aofs[5];
  #pragma unroll
  for(int r=0;r<5;r++){
    int c = r*256 + tid; int row = c>>2, at = c&3;
    asrc[r] = Abase + (size_t)row*C_ + at*8;
    aofs[r] = row*36 + at*8;
  }
  bool a4 = (tid < 32);

  uint4 rb[4], ra[5];
  // prologue: A(ci=0) + B(0) + load B(1)
  #pragma unroll
  for(int r=0;r<4;r++) ra[r] = *(const uint4*)(asrc[r]);
  if(a4) ra[4] = *(const uint4*)(asrc[4]);
  #pragma unroll
  for(int r=0;r<4;r++) rb[r] = *(const uint4*)(bsrc[r]);              // t=0, ci=0
  #pragma unroll
  for(int r=0;r<4;r++) *(uint4*)(&As[aofs[r]]) = ra[r];
  if(a4) *(uint4*)(&As[aofs[4]]) = ra[4];
  #pragma unroll
  for(int r=0;r<4;r++) *(uint4*)(&Bs[0][bofs[r]]) = rb[r];
  #pragma unroll
  for(int r=0;r<4;r++) rb[r] = *(const uint4*)(bsrc[r] + 256);        // t=1, ci=0
  __syncthreads();

  int cb = 0;
  int tL = 2, ciL = 0;    // next B chunk to load = (tL, ciL)
  for(int ci=0; ci<8; ci++){
    for(int t=0;t<9;t++){
      int s = ci*9 + t;
      if(s < 71){
        #pragma unroll
        for(int r=0;r<4;r++) *(uint4*)(&Bs[cb^1][bofs[r]]) = rb[r];   // B(s+1) -> other buf
        if(s < 70){
          int off = tL*256 + ciL*32;
          #pragma unroll
          for(int r=0;r<4;r++) rb[r] = *(const uint4*)(bsrc[r] + off); // issue B(s+2)
          if(++tL == 9){ tL = 0; ciL++; }
        }
      }
      if(t==7 && ci<7){                                               // prefetch A(ci+1) regs
        int off = (ci+1)*32;
        #pragma unroll
        for(int r=0;r<4;r++) ra[r] = *(const uint4*)(asrc[r] + off);
        if(a4) ra[4] = *(const uint4*)(asrc[4] + off);
      }
      int dy = (t*11)>>5, dx = t - dy*3;
      bf16x8 af[4], bfv[8];
      #pragma unroll
      for(int mf=0;mf<4;mf++){
        int ipix = (hr_[mf]+dy)*66 + wp_[mf] + dx;
        af[mf] = ldfrag(&As[ipix*36 + qd*8]);
      }
      #pragma unroll
      for(int nf=0;nf<8;nf++){
        int n = wn*128 + nf*16 + ln;
        bfv[nf] = ldfrag(&Bs[cb][n*36 + qd*8]);
      }
      #pragma unroll
      for(int mf=0;mf<4;mf++)
        #pragma unroll
        for(int nf=0;nf<8;nf++)
          acc[mf][nf] = __builtin_amdgcn_mfma_f32_16x16x32_bf16(af[mf], bfv[nf], acc[mf][nf], 0,0,0);
      __syncthreads();
      if(t==8 && ci<7){                                               // A(ci+1) regs -> LDS
        #pragma unroll
        for(int r=0;r<4;r++) *(uint4*)(&As[aofs[r]]) = ra[r];
        if(a4) *(uint4*)(&As[aofs[4]]) = ra[4];
        __syncthreads();
      }
      cb ^= 1;
    }
  }
  // epilogue: bias, h-write, GN partial stats
  float s[4]={0,0,0,0}, q[4]={0,0,0,0};
  int p0 = hp*128;
  for(int nf=0;nf<8;nf++){
    int n = wn*128 + nf*16 + ln;
    float bias = conv_b[n];
    for(int mf=0;mf<4;mf++){
      for(int r=0;r<4;r++){
        int p = wm*64 + mf*16 + qd*4 + r;
        float v = acc[mf][nf][r] + bias;
        h[((size_t)(b*HW_ + p0 + p))*C_ + n] = f2bf(v);
        s[nf>>1]+=v; q[nf>>1]+=v*v;
      }
    }
  }
  for(int off=32;off>=1;off>>=1){
    #pragma unroll
    for(int g=0;g<4;g++){ s[g]+=__shfl_down(s[g],off,64); q[g]+=__shfl_down(q[g],off,64); }
  }
  if(lane==0){
    #pragma unroll
    for(int g=0;g<4;g++){
      atomicAdd(&stats[(b*8 + wn*4 + g)*2+0], s[g]);
      atomicAdd(&stats[(b*8 + wn*4 + g)*2+1], q[g]);
    }
  }
}

// ---------------- K5: fused GN+SiLU+qproj: q = silu(gn(h)) @ wq^T + bq ----------------
__global__ __launch_bounds__(256, 2) void k_qgn(const u16* __restrict__ hbuf, const u16* __restrict__ wqB,
    const float* __restrict__ stats, const float* __restrict__ gnw, const float* __restrict__ gnb,
    const float* __restrict__ bq, u16* __restrict__ qb){
  __shared__ u16 As[128*32];
  __shared__ u16 Bs[256*32];
  int mt = blockIdx.x;
  int b = mt >> 5;
  int tid = threadIdx.x;
  int w = tid>>6, lane = tid&63, ln = lane&15, qd = lane>>4;
  int wm = w&1, wn = w>>1;
  int pr = tid>>1, half = tid&1;
  const u16* hsrc = hbuf + ((size_t)(mt*128+pr))*256 + half*16;
  f32x4 acc[4][8] = {};
  uint4 ra0, ra1, rb0, rb1;
  ra0 = *(const uint4*)(hsrc);
  ra1 = *(const uint4*)(hsrc + 8);
  for(int kt=0; kt<8; kt++){
    float sm = stats[(b*8+kt)*2], qm = stats[(b*8+kt)*2+1];
    float mean = sm*(1.f/131072.f);
    float rstd = rsqrtf(qm*(1.f/131072.f) - mean*mean + EPS_);
    int c0 = kt*32 + half*16;
    float4 gw0 = *(const float4*)(gnw+c0), gw1 = *(const float4*)(gnw+c0+4);
    float4 gw2 = *(const float4*)(gnw+c0+8), gw3 = *(const float4*)(gnw+c0+12);
    float4 gb0 = *(const float4*)(gnb+c0), gb1 = *(const float4*)(gnb+c0+4);
    float4 gb2 = *(const float4*)(gnb+c0+8), gb3 = *(const float4*)(gnb+c0+12);
    float gwv[16] = {gw0.x,gw0.y,gw0.z,gw0.w, gw1.x,gw1.y,gw1.z,gw1.w,
                     gw2.x,gw2.y,gw2.z,gw2.w, gw3.x,gw3.y,gw3.z,gw3.w};
    float gbv[16] = {gb0.x,gb0.y,gb0.z,gb0.w, gb1.x,gb1.y,gb1.z,gb1.w,
                     gb2.x,gb2.y,gb2.z,gb2.w, gb3.x,gb3.y,gb3.z,gb3.w};
    u16 inu[16];
    ((uint4*)inu)[0] = ra0; ((uint4*)inu)[1] = ra1;
    u16 outu[16];
    #pragma unroll
    for(int j=0;j<16;j++){
      float v = bf2f(inu[j]);
      v = (v-mean)*rstd*gwv[j] + gbv[j];
      float s = v/(1.f+__expf(-v));
      outu[j] = f2bf(s);
    }
    u16* adst = &As[pr*32 + half*16];
    ((uint4*)adst)[0] = ((uint4*)outu)[0];
    ((uint4*)adst)[1] = ((uint4*)outu)[1];
    #pragma unroll
    for(int r=0;r<4;r++){
      int c = r*256 + tid;
      int co = c>>2, atom = c&3;
      g2l16(wqB + (size_t)co*256 + kt*32 + atom*8, &Bs[c*8]);
    }
    if(kt<7){
      rb0 = *(const uint4*)(hsrc + (kt+1)*32);
      rb1 = *(const uint4*)(hsrc + (kt+1)*32 + 8);
    }
    __syncthreads();
    bf16x8 af[4], bfv[8];
    #pragma unroll
    for(int mf=0;mf<4;mf++) af[mf] = ldfrag(&As[(wm*64+mf*16+ln)*32 + qd*8]);
    #pragma unroll
    for(int nf=0;nf<8;nf++) bfv[nf] = ldfrag(&Bs[(wn*128+nf*16+ln)*32 + qd*8]);
    #pragma unroll
    for(int mf=0;mf<4;mf++)
      #pragma unroll
      for(int nf=0;nf<8;nf++)
        acc[mf][nf] = __builtin_amdgcn_mfma_f32_16x16x32_bf16(af[mf], bfv[nf], acc[mf][nf], 0,0,0);
    __syncthreads();
    ra0 = rb0; ra1 = rb1;
  }
  for(int nf=0;nf<8;nf++){
    int n = wn*128 + nf*16 + ln;
    float bias = bq[n];
    for(int mf=0;mf<4;mf++){
      for(int r=0;r<4;r++){
        int ml = wm*64 + mf*16 + qd*4 + r;
        qb[((size_t)(mt*128+ml))*256 + n] = f2bf(acc[mf][nf][r]+bias);
      }
    }
  }
}

// ---------------- K6: k,v = ctx @ {wk,wv}^T + b, 64x64 tiles, 160 blocks ----------------
__global__ __launch_bounds__(256) void k_kvproj(const u16* __restrict__ ctxB, const u16* __restrict__ wkvB,
    const float* __restrict__ bk, const float* __restrict__ bv,
    u16* __restrict__ kb, u16* __restrict__ vT){
  __shared__ u16 As[64*128];
  __shared__ u16 Bs[64*128];
  int bid = blockIdx.x;
  int nt = bid & 7, mt = bid >> 3;
  int n0 = nt*64, m0 = mt*64;
  int tid=threadIdx.x, w=tid>>6, lane=tid&63, ln=lane&15, qd=lane>>4;
  int wm = w&1, wn = w>>1;
  f32x4 acc[2][2]={};
  for(int kt=0;kt<6;kt++){
    #pragma unroll
    for(int r=0;r<4;r++){
      int c = r*256 + tid;
      int row = c>>4, atom = c&15;
      g2l16(ctxB + ((size_t)(m0+row)*768 + kt*128 + atom*8), &As[c*8]);
      g2l16(wkvB + ((size_t)(n0+row)*768 + kt*128 + atom*8), &Bs[c*8]);
    }
    __syncthreads();
    #pragma unroll
    for(int kk=0;kk<4;kk++){
      bf16x8 af[2], bfv[2];
      #pragma unroll
      for(int mf=0;mf<2;mf++) af[mf]=ldfrag(&As[(wm*32+mf*16+ln)*128 + kk*32 + qd*8]);
      #pragma unroll
      for(int nf=0;nf<2;nf++) bfv[nf]=ldfrag(&Bs[(wn*32+nf*16+ln)*128 + kk*32 + qd*8]);
      #pragma unroll
      for(int mf=0;mf<2;mf++)
        #pragma unroll
        for(int nf=0;nf<2;nf++)
          acc[mf][nf]=__builtin_amdgcn_mfma_f32_16x16x32_bf16(af[mf],bfv[nf],acc[mf][nf],0,0,0);
    }
    __syncthreads();
  }
  for(int mf=0;mf<2;mf++) for(int nf=0;nf<2;nf++){
    int ng = n0 + wn*32 + nf*16 + ln;
    float bias = ng<256 ? bk[ng] : bv[ng-256];
    for(int r=0;r<4;r++){
      int mg = m0 + wm*32 + mf*16 + qd*4 + r;
      if(mg<1232){
        float v=acc[mf][nf][r]+bias;
        int bb=mg/77, l=mg-bb*77;
        if(ng<256) kb[((size_t)(bb*77+l))*256+ng]=f2bf(v);
        else vT[((size_t)(bb*256+(ng-256)))*96 + l]=f2bf(v);
      }
    }
  }
}

// ---------------- K7: attention per (b, 128-pixel q tile) ----------------
__global__ __launch_bounds__(256) void k_attn(const u16* __restrict__ qg, const u16* __restrict__ kb,
    const u16* __restrict__ vT, u16* __restrict__ ob){
  __shared__ u16 Qs[4096];        // 128 x 32
  __shared__ u16 KVs[4096];       // up to 128 x 32
  __shared__ u16 Sb[128*84];      // S scores, bf16, padded
  __shared__ u16 Pb[128*104];     // P, bf16, k-padded to 96 (+8)
  int bid=blockIdx.x; int b=bid>>5, qt=bid&31; int p0=qt*128;
  int tid=threadIdx.x, w=tid>>6, lane=tid&63, ln=lane&15, qd=lane>>4;
  int srow=tid>>2, koff=(tid&3)*8;
  f32x4 Sa[2][5]={};
  for(int kt=0;kt<8;kt++){
    for(int j=0;j<2;j++){
      int m=srow+j*64;
      g2l16(qg + ((size_t)(b*HW_+p0+m)*256 + kt*32+koff), &Qs[(size_t)tid*8+j*2048]);
    }
    for(int j=0;j<2;j++){
      int cja = tid + j*256;
      if(cja < 320){
        int l = cja>>2, ko2=(cja&3)*8;
        g2l16(kb + ((size_t)(b*77+l)*256 + kt*32+ko2), &KVs[(size_t)cja*8]);
      }
    }
    __syncthreads();
    bf16x8 af[2], bfv[5];
    for(int mf=0;mf<2;mf++) af[mf]=ldfrag(&Qs[(w*32+mf*16+ln)*32+qd*8]);
    for(int nf=0;nf<5;nf++) bfv[nf]=ldfrag(&KVs[(nf*16+ln)*32+qd*8]);
    for(int mf=0;mf<2;mf++) for(int nf=0;nf<5;nf++)
      Sa[mf][nf]=__builtin_amdgcn_mfma_f32_16x16x32_bf16(af[mf],bfv[nf],Sa[mf][nf],0,0,0);
    __syncthreads();
  }
  for(int mf=0;mf<2;mf++) for(int nf=0;nf<5;nf++) for(int r=0;r<4;r++){
    int ml=w*32+mf*16+qd*4+r, nl=nf*16+ln;
    Sb[ml*84+nl]=f2bf(Sa[mf][nf][r]*0.0625f);
  }
  __syncthreads();
  if(tid<128){
    const u16* srp = &Sb[tid*84];
    u16* prow = &Pb[tid*104];
    float mx=-1e30f;
    for(int j2=0;j2<77;j2++){ float v=bf2f(srp[j2]); mx=fmaxf(mx,v); }
    float sum=0.f;
    for(int j2=0;j2<77;j2++){ float e=__expf(bf2f(srp[j2])-mx); sum+=e; prow[j2]=f2bf(e); }
    float inv=1.f/sum;
    for(int j2=0;j2<77;j2++){ prow[j2]=f2bf(bf2f(prow[j2])*inv); }
    for(int j2=77;j2<104;j2++) prow[j2]=0;
  }
  __syncthreads();
  for(int nh=0;nh<2;nh++){
    f32x4 Oa[2][8]={};
    for(int kt2=0;kt2<3;kt2++){
      for(int j=0;j<2;j++){
        int chunk=tid+j*256;
        int co=chunk>>2, ko2=(chunk&3)*8;
        g2l16(vT + ((size_t)(b*256+nh*128+co)*96 + kt2*32+ko2), &KVs[(size_t)chunk*8]);
      }
      __syncthreads();
      bf16x8 af[2], bfv[8];
      for(int mf=0;mf<2;mf++) af[mf]=ldfrag(&Pb[(w*32+mf*16+ln)*104 + kt2*32+qd*8]);
      for(int nf=0;nf<8;nf++) bfv[nf]=ldfrag(&KVs[(nf*16+ln)*32+qd*8]);
      for(int mf=0;mf<2;mf++) for(int nf=0;nf<8;nf++)
        Oa[mf][nf]=__builtin_amdgcn_mfma_f32_16x16x32_bf16(af[mf],bfv[nf],Oa[mf][nf],0,0,0);
      __syncthreads();
    }
    for(int mf=0;mf<2;mf++) for(int nf=0;nf<8;nf++) for(int r=0;r<4;r++){
      int ml=w*32+mf*16+qd*4+r, nl=nh*128+nf*16+ln;
      ob[((size_t)(b*HW_+p0+ml))*256+nl]=f2bf(Oa[mf][nf][r]);
    }
  }
}

// ---------------- K8: out = x + (wo @ o^T) + bo, written NCHW ----------------
__global__ __launch_bounds__(256) void k_oproj(const u16* __restrict__ ob, const u16* __restrict__ woB,
    const float* __restrict__ bo, const float* __restrict__ x, float* __restrict__ outp){
  __shared__ u16 As[128*32];
  __shared__ u16 Bs[128*32];
  int bid=blockIdx.x;
  int b=bid>>6; int rr=bid&63; int cm=rr>>5, pt=rr&31;
  int c0=cm*128, p0=pt*128;
  int tid=threadIdx.x, w=tid>>6, lane=tid&63, ln=lane&15, qd=lane>>4, wm=w>>1, wn=w&1;
  int srow=tid>>2, koff=(tid&3)*8;
  f32x4 acc[4][4]={};
  for(int kt=0;kt<8;kt++){
    for(int j=0;j<2;j++){
      int m=srow+j*64;
      g2l16(woB + ((size_t)(c0+m)*256 + kt*32+koff),        &As[(size_t)tid*8+j*2048]);
      g2l16(ob  + ((size_t)(b*HW_+p0+m)*256 + kt*32+koff),  &Bs[(size_t)tid*8+j*2048]);
    }
    __syncthreads();
    bf16x8 af[4], bfv[4];
    for(int mf=0;mf<4;mf++) af[mf]=ldfrag(&As[(wm*64+mf*16+ln)*32+qd*8]);
    for(int nf=0;nf<4;nf++) bfv[nf]=ldfrag(&Bs[(wn*64+nf*16+ln)*32+qd*8]);
    for(int mf=0;mf<4;mf++) for(int nf=0;nf<4;nf++)
      acc[mf][nf]=__builtin_amdgcn_mfma_f32_16x16x32_bf16(af[mf],bfv[nf],acc[mf][nf],0,0,0);
    __syncthreads();
  }
  for(int mf=0;mf<4;mf++) for(int r=0;r<4;r++){
    int cl=c0+wm*64+mf*16+qd*4+r;
    float bias=bo[cl];
    for(int nf=0;nf<4;nf++){
      int pl=p0+wn*64+nf*16+ln;
      size_t idx=((size_t)(b*C_+cl))*HW_+pl;
      outp[idx]=x[idx]+acc[mf][nf][r]+bias;
    }
  }
}

extern "C" void kernel_launch(void* const* d_in, const int* in_sizes, int n_in,
                              void* d_out, int out_size, void* d_ws, size_t ws_size,
                              hipStream_t stream){
  const float* x      = (const float*)d_in[0];
  const float* ctx    = (const float*)d_in[1];
  const float* conv_w = (const float*)d_in[2];
  const float* conv_b = (const float*)d_in[3];
  const float* gnw    = (const float*)d_in[4];
  const float* gnb    = (const float*)d_in[5];
  const float* wq     = (const float*)d_in[6];
  const float* bq     = (const float*)d_in[7];
  const float* wk     = (const float*)d_in[8];
  const float* bk     = (const float*)d_in[9];
  const float* wv     = (const float*)d_in[10];
  const float* bv     = (const float*)d_in[11];
  const float* wo     = (const float*)d_in[12];
  const float* bo     = (const float*)d_in[13];
  char* ws = (char*)d_ws;
  u16* xpT  = (u16*)(ws + 0);            // 35,684,352 ; reused as q after conv
  u16* wBt  = (u16*)(ws + 35684352);     //  1,179,648
  u16* wqB  = (u16*)(ws + 36864000);     //    131,072
  u16* wkvB = (u16*)(ws + 36995072);     //    786,432
  u16* woB  = (u16*)(ws + 37781504);     //    131,072
  u16* ctxB = (u16*)(ws + 37912576);     //  1,892,352 (+74KB OOB read slack into hbuf)
  u16* hbuf = (u16*)(ws + 39804928);     // 33,554,432 (raw conv output)
  u16* kbv  = (u16*)(ws + 73359360);     //    630,784
  u16* vT   = (u16*)(ws + 73990144);     //    786,432
  u16* obuf = (u16*)(ws + 74776576);     // 33,554,432
  float* stats = (float*)(ws + 108331008); // 2048
  u16* qb = xpT;
  float* outp = (float*)d_out;

  k_pad   <<<1056, 256, 0, stream>>>(x, xpT);
  k_repack<<<8050, 256, 0, stream>>>(conv_w, wq, wo, wk, wv, ctx, wBt, wqB, woB, wkvB, ctxB, stats);
  k_conv  <<<512,  256, 0, stream>>>(xpT, wBt, conv_b, hbuf, stats);
  k_qgn   <<<512,  256, 0, stream>>>(hbuf, wqB, stats, gnw, gnb, bq, qb);
  k_kvproj<<<160,  256, 0, stream>>>(ctxB, wkvB, bk, bv, kbv, vT);
  k_attn  <<<512,  256, 0, stream>>>(qb, kbv, vT, obuf);
  k_oproj <<<1024, 256, 0, stream>>>(obuf, woB, bo, x, outp);
}

// Round 9
// 369.707 us; speedup vs baseline: 1.8095x; 1.8095x over previous
//
#include <hip/hip_runtime.h>
#include <stdint.h>

#define B_  16
#define C_  256
#define HW_ 4096
#define Hp  66
#define PP  4356   // 66*66
#define EPS_ 1e-5f

typedef unsigned short u16;
typedef unsigned int   u32;
typedef __attribute__((ext_vector_type(4))) float  f32x4;
typedef __attribute__((ext_vector_type(8))) __bf16 bf16x8;
typedef __attribute__((ext_vector_type(8))) u16    u16x8;

__device__ __forceinline__ float bf2f(u16 u){ u32 x = ((u32)u)<<16; float f; __builtin_memcpy(&f,&x,4); return f; }
__device__ __forceinline__ u16 f2bf(float f){ u32 x; __builtin_memcpy(&x,&f,4); u32 r = x + 0x7fffu + ((x>>16)&1u); return (u16)(r>>16); }

__device__ __forceinline__ void g2l16(const void* g, void* l){
  __builtin_amdgcn_global_load_lds((__attribute__((address_space(1))) void*)(void*)g,
                                   (__attribute__((address_space(3))) void*)l, 16, 0, 0);
}
__device__ __forceinline__ bf16x8 ldfrag(const u16* p){
  u16x8 r = *(const u16x8*)p;
  return __builtin_bit_cast(bf16x8, r);
}

// ---------------- K0: pad+transpose x AND repack weights (merged, block-range split) -----
__global__ __launch_bounds__(256) void k_prep(const float* __restrict__ x, u16* __restrict__ xpT,
    const float* __restrict__ conv_w, const float* __restrict__ wq, const float* __restrict__ wo,
    const float* __restrict__ wk, const float* __restrict__ wv, const float* __restrict__ ctx,
    u16* __restrict__ wBt, u16* __restrict__ wqB, u16* __restrict__ woB,
    u16* __restrict__ wkvB, u16* __restrict__ ctxB, float* __restrict__ stats){
  __shared__ float Lt[64*65];
  int bid = blockIdx.x; int tid = threadIdx.x;
  if(bid >= 1056){
    int i = (bid-1056)*256 + tid;
    if(i < 589824){ int co = i/2304, k = i - co*2304; int t = k>>8, ci = k&255;
      wBt[i] = f2bf(conv_w[(co*256+ci)*9 + t]); return; }
    i -= 589824;
    if(i < 65536){ wqB[i] = f2bf(wq[i]); return; } i -= 65536;
    if(i < 65536){ woB[i] = f2bf(wo[i]); return; } i -= 65536;
    if(i < 196608){ wkvB[i] = f2bf(wk[i]); return; } i -= 196608;
    if(i < 196608){ wkvB[196608+i] = f2bf(wv[i]); return; } i -= 196608;
    if(i < 946176){ ctxB[i] = f2bf(ctx[i]); return; } i -= 946176;
    if(i < 512){ stats[i] = 0.f; }
    return;
  }
  int b = bid/66, hh = bid - b*66;
  u16* rowbase = xpT + (size_t)(b*PP + hh*Hp)*C_;
  if(hh==0 || hh==65){
    u32* p = (u32*)rowbase;
    for(int i=tid;i<66*C_/2;i+=256) p[i]=0u;
    return;
  }
  if(tid<128) ((u32*)rowbase)[tid]=0u;                 // ww = 0 border
  else ((u32*)(rowbase + 65*C_))[tid-128]=0u;          // ww = 65 border
  int h = hh-1;
  for(int cc=0; cc<4; cc++){
    int c0=cc*64;
    int ci = tid>>2, w0 = (tid&3)*16;
    const float* xs = x + ((size_t)(b*C_ + c0+ci)*HW_) + h*64 + w0;
    for(int j=0;j<4;j++){
      float4 v = *(const float4*)(xs + j*4);
      Lt[ci*65 + w0 + j*4 + 0] = v.x;
      Lt[ci*65 + w0 + j*4 + 1] = v.y;
      Lt[ci*65 + w0 + j*4 + 2] = v.z;
      Lt[ci*65 + w0 + j*4 + 3] = v.w;
    }
    __syncthreads();
    int w = tid>>2, cj = (tid&3)*16;
    union { u16 u[16]; uint4 v[2]; } outu;
    for(int j=0;j<16;j++) outu.u[j] = f2bf(Lt[(cj+j)*65 + w]);
    uint4* dst = (uint4*)(rowbase + (size_t)(w+1)*C_ + c0 + cj);
    dst[0]=outu.v[0]; dst[1]=outu.v[1];
    __syncthreads();
  }
}

// ---------------- K2: conv implicit GEMM, A-slab resident across taps (round-5 version) --
__global__ __launch_bounds__(256, 2) void k_conv(const u16* __restrict__ xpT, const u16* __restrict__ wBt,
    const float* __restrict__ conv_b, u16* __restrict__ h, float* __restrict__ stats){
  __shared__ u16 As[264*32];
  __shared__ u16 Bs[256*32];
  int bid = blockIdx.x;
  int b = bid >> 5, hp = bid & 31;
  int tid = threadIdx.x;
  int w = tid>>6, lane = tid&63, ln = lane&15, qd = lane>>4;
  int wm = w&1, wn = w>>1;
  const u16* Abase = xpT + (size_t)(b*PP + hp*132)*C_;
  f32x4 acc[4][8] = {};
  int hr_[4], wp_[4];
  #pragma unroll
  for(int mf=0;mf<4;mf++){ int p = wm*64 + mf*16 + ln; hr_[mf] = p>>6; wp_[mf] = p&63; }

  for(int ci=0; ci<8; ci++){
    int ci0 = ci*32;
    #pragma unroll
    for(int r=0;r<5;r++){
      int c = r*256 + tid;
      if(c < 1056){
        int ipix = c>>2, atom = c&3;
        g2l16(Abase + (size_t)ipix*C_ + ci0 + atom*8, &As[c*8]);
      }
    }
    for(int t=0;t<9;t++){
      int dy = (t*11)>>5, dx = t - dy*3;
      #pragma unroll
      for(int r=0;r<4;r++){
        int c = r*256 + tid;
        int co = c>>2, atom = c&3;
        g2l16(wBt + (size_t)co*2304 + t*256 + ci0 + atom*8, &Bs[c*8]);
      }
      __syncthreads();
      bf16x8 af[4], bfv[8];
      #pragma unroll
      for(int mf=0;mf<4;mf++){
        int ipix = (hr_[mf]+dy)*66 + wp_[mf] + dx;
        af[mf] = ldfrag(&As[ipix*32 + qd*8]);
      }
      #pragma unroll
      for(int nf=0;nf<8;nf++) bfv[nf] = ldfrag(&Bs[(wn*128+nf*16+ln)*32 + qd*8]);
      #pragma unroll
      for(int mf=0;mf<4;mf++)
        #pragma unroll
        for(int nf=0;nf<8;nf++)
          acc[mf][nf] = __builtin_amdgcn_mfma_f32_16x16x32_bf16(af[mf], bfv[nf], acc[mf][nf], 0,0,0);
      __syncthreads();
    }
  }
  float s[4]={0,0,0,0}, q[4]={0,0,0,0};
  int p0 = hp*128;
  for(int nf=0;nf<8;nf++){
    int n = wn*128 + nf*16 + ln;
    float bias = conv_b[n];
    for(int mf=0;mf<4;mf++){
      for(int r=0;r<4;r++){
        int p = wm*64 + mf*16 + qd*4 + r;
        float v = acc[mf][nf][r] + bias;
        h[((size_t)(b*HW_ + p0 + p))*C_ + n] = f2bf(v);
        s[nf>>1]+=v; q[nf>>1]+=v*v;
      }
    }
  }
  for(int off=32;off>=1;off>>=1){
    #pragma unroll
    for(int g=0;g<4;g++){ s[g]+=__shfl_down(s[g],off,64); q[g]+=__shfl_down(q[g],off,64); }
  }
  if(lane==0){
    #pragma unroll
    for(int g=0;g<4;g++){
      atomicAdd(&stats[(b*8 + wn*4 + g)*2+0], s[g]);
      atomicAdd(&stats[(b*8 + wn*4 + g)*2+1], q[g]);
    }
  }
}

// ---------------- K5: fused GN+SiLU+qproj: q = silu(gn(h)) @ wq^T + bq ----------------
__global__ __launch_bounds__(256, 2) void k_qgn(const u16* __restrict__ hbuf, const u16* __restrict__ wqB,
    const float* __restrict__ stats, const float* __restrict__ gnw, const float* __restrict__ gnb,
    const float* __restrict__ bq, u16* __restrict__ qb){
  __shared__ u16 As[128*32];
  __shared__ u16 Bs[256*32];
  int mt = blockIdx.x;
  int b = mt >> 5;
  int tid = threadIdx.x;
  int w = tid>>6, lane = tid&63, ln = lane&15, qd = lane>>4;
  int wm = w&1, wn = w>>1;
  int pr = tid>>1, half = tid&1;
  const u16* hsrc = hbuf + ((size_t)(mt*128+pr))*256 + half*16;
  f32x4 acc[4][8] = {};
  uint4 ra0, ra1, rb0, rb1;
  ra0 = *(const uint4*)(hsrc);
  ra1 = *(const uint4*)(hsrc + 8);
  for(int kt=0; kt<8; kt++){
    float sm = stats[(b*8+kt)*2], qm = stats[(b*8+kt)*2+1];
    float mean = sm*(1.f/131072.f);
    float rstd = rsqrtf(qm*(1.f/131072.f) - mean*mean + EPS_);
    int c0 = kt*32 + half*16;
    float4 gw0 = *(const float4*)(gnw+c0), gw1 = *(const float4*)(gnw+c0+4);
    float4 gw2 = *(const float4*)(gnw+c0+8), gw3 = *(const float4*)(gnw+c0+12);
    float4 gb0 = *(const float4*)(gnb+c0), gb1 = *(const float4*)(gnb+c0+4);
    float4 gb2 = *(const float4*)(gnb+c0+8), gb3 = *(const float4*)(gnb+c0+12);
    float gwv[16] = {gw0.x,gw0.y,gw0.z,gw0.w, gw1.x,gw1.y,gw1.z,gw1.w,
                     gw2.x,gw2.y,gw2.z,gw2.w, gw3.x,gw3.y,gw3.z,gw3.w};
    float gbv[16] = {gb0.x,gb0.y,gb0.z,gb0.w, gb1.x,gb1.y,gb1.z,gb1.w,
                     gb2.x,gb2.y,gb2.z,gb2.w, gb3.x,gb3.y,gb3.z,gb3.w};
    u16 inu[16];
    ((uint4*)inu)[0] = ra0; ((uint4*)inu)[1] = ra1;
    u16 outu[16];
    #pragma unroll
    for(int j=0;j<16;j++){
      float v = bf2f(inu[j]);
      v = (v-mean)*rstd*gwv[j] + gbv[j];
      float s = v/(1.f+__expf(-v));
      outu[j] = f2bf(s);
    }
    u16* adst = &As[pr*32 + half*16];
    ((uint4*)adst)[0] = ((uint4*)outu)[0];
    ((uint4*)adst)[1] = ((uint4*)outu)[1];
    #pragma unroll
    for(int r=0;r<4;r++){
      int c = r*256 + tid;
      int co = c>>2, atom = c&3;
      g2l16(wqB + (size_t)co*256 + kt*32 + atom*8, &Bs[c*8]);
    }
    if(kt<7){
      rb0 = *(const uint4*)(hsrc + (kt+1)*32);
      rb1 = *(const uint4*)(hsrc + (kt+1)*32 + 8);
    }
    __syncthreads();
    bf16x8 af[4], bfv[8];
    #pragma unroll
    for(int mf=0;mf<4;mf++) af[mf] = ldfrag(&As[(wm*64+mf*16+ln)*32 + qd*8]);
    #pragma unroll
    for(int nf=0;nf<8;nf++) bfv[nf] = ldfrag(&Bs[(wn*128+nf*16+ln)*32 + qd*8]);
    #pragma unroll
    for(int mf=0;mf<4;mf++)
      #pragma unroll
      for(int nf=0;nf<8;nf++)
        acc[mf][nf] = __builtin_amdgcn_mfma_f32_16x16x32_bf16(af[mf], bfv[nf], acc[mf][nf], 0,0,0);
    __syncthreads();
    ra0 = rb0; ra1 = rb1;
  }
  for(int nf=0;nf<8;nf++){
    int n = wn*128 + nf*16 + ln;
    float bias = bq[n];
    for(int mf=0;mf<4;mf++){
      for(int r=0;r<4;r++){
        int ml = wm*64 + mf*16 + qd*4 + r;
        qb[((size_t)(mt*128+ml))*256 + n] = f2bf(acc[mf][nf][r]+bias);
      }
    }
  }
}

// ---------------- K6: k,v = ctx @ {wk,wv}^T + b, 64x64 tiles, 160 blocks ----------------
__global__ __launch_bounds__(256) void k_kvproj(const u16* __restrict__ ctxB, const u16* __restrict__ wkvB,
    const float* __restrict__ bk, const float* __restrict__ bv,
    u16* __restrict__ kb, u16* __restrict__ vT){
  __shared__ u16 As[64*128];
  __shared__ u16 Bs[64*128];
  int bid = blockIdx.x;
  int nt = bid & 7, mt = bid >> 3;
  int n0 = nt*64, m0 = mt*64;
  int tid=threadIdx.x, w=tid>>6, lane=tid&63, ln=lane&15, qd=lane>>4;
  int wm = w&1, wn = w>>1;
  f32x4 acc[2][2]={};
  for(int kt=0;kt<6;kt++){
    #pragma unroll
    for(int r=0;r<4;r++){
      int c = r*256 + tid;
      int row = c>>4, atom = c&15;
      g2l16(ctxB + ((size_t)(m0+row)*768 + kt*128 + atom*8), &As[c*8]);
      g2l16(wkvB + ((size_t)(n0+row)*768 + kt*128 + atom*8), &Bs[c*8]);
    }
    __syncthreads();
    #pragma unroll
    for(int kk=0;kk<4;kk++){
      bf16x8 af[2], bfv[2];
      #pragma unroll
      for(int mf=0;mf<2;mf++) af[mf]=ldfrag(&As[(wm*32+mf*16+ln)*128 + kk*32 + qd*8]);
      #pragma unroll
      for(int nf=0;nf<2;nf++) bfv[nf]=ldfrag(&Bs[(wn*32+nf*16+ln)*128 + kk*32 + qd*8]);
      #pragma unroll
      for(int mf=0;mf<2;mf++)
        #pragma unroll
        for(int nf=0;nf<2;nf++)
          acc[mf][nf]=__builtin_amdgcn_mfma_f32_16x16x32_bf16(af[mf],bfv[nf],acc[mf][nf],0,0,0);
    }
    __syncthreads();
  }
  for(int mf=0;mf<2;mf++) for(int nf=0;nf<2;nf++){
    int ng = n0 + wn*32 + nf*16 + ln;
    float bias = ng<256 ? bk[ng] : bv[ng-256];
    for(int r=0;r<4;r++){
      int mg = m0 + wm*32 + mf*16 + qd*4 + r;
      if(mg<1232){
        float v=acc[mf][nf][r]+bias;
        int bb=mg/77, l=mg-bb*77;
        if(ng<256) kb[((size_t)(bb*77+l))*256+ng]=f2bf(v);
        else vT[((size_t)(bb*256+(ng-256)))*96 + l]=f2bf(v);
      }
    }
  }
}

// ---------------- K7: attention per (b, 128-pixel q tile) ----------------
// Softmax: Sb stride 88 (16B-aligned rows, conflict-free b128), vectorized 2-pass,
// P left UNNORMALIZED; O rows scaled by invr[row] in the PV epilogue.
__global__ __launch_bounds__(256) void k_attn(const u16* __restrict__ qg, const u16* __restrict__ kb,
    const u16* __restrict__ vT, u16* __restrict__ ob){
  __shared__ u16 Qs[4096];        // 128 x 32
  __shared__ u16 KVs[4096];       // up to 128 x 32
  __shared__ u16 Sb[128*88];      // S scores, bf16, 88-stride
  __shared__ u16 Pb[128*104];     // P (unnormalized), bf16, k-padded to 96 (+8)
  __shared__ float invr[128];
  int bid=blockIdx.x; int b=bid>>5, qt=bid&31; int p0=qt*128;
  int tid=threadIdx.x, w=tid>>6, lane=tid&63, ln=lane&15, qd=lane>>4;
  int srow=tid>>2, koff=(tid&3)*8;
  f32x4 Sa[2][5]={};
  for(int kt=0;kt<8;kt++){
    for(int j=0;j<2;j++){
      int m=srow+j*64;
      g2l16(qg + ((size_t)(b*HW_+p0+m)*256 + kt*32+koff), &Qs[(size_t)tid*8+j*2048]);
    }
    for(int j=0;j<2;j++){
      int cja = tid + j*256;
      if(cja < 320){
        int l = cja>>2, ko2=(cja&3)*8;
        g2l16(kb + ((size_t)(b*77+l)*256 + kt*32+ko2), &KVs[(size_t)cja*8]);
      }
    }
    __syncthreads();
    bf16x8 af[2], bfv[5];
    for(int mf=0;mf<2;mf++) af[mf]=ldfrag(&Qs[(w*32+mf*16+ln)*32+qd*8]);
    for(int nf=0;nf<5;nf++) bfv[nf]=ldfrag(&KVs[(nf*16+ln)*32+qd*8]);
    for(int mf=0;mf<2;mf++) for(int nf=0;nf<5;nf++)
      Sa[mf][nf]=__builtin_amdgcn_mfma_f32_16x16x32_bf16(af[mf],bfv[nf],Sa[mf][nf],0,0,0);
    __syncthreads();
  }
  for(int mf=0;mf<2;mf++) for(int nf=0;nf<5;nf++) for(int r=0;r<4;r++){
    int ml=w*32+mf*16+qd*4+r, nl=nf*16+ln;
    Sb[ml*88+nl]=f2bf(Sa[mf][nf][r]*0.0625f);
  }
  __syncthreads();
  if(tid<128){
    u16* srp = &Sb[tid*88];
    srp[77]=0xFF80u; srp[78]=0xFF80u; srp[79]=0xFF80u;   // -inf tail pad
    float mx=-1e30f;
    #pragma unroll
    for(int c8=0;c8<10;c8++){
      u16x8 v = *(const u16x8*)(srp + c8*8);
      #pragma unroll
      for(int j=0;j<8;j++) mx = fmaxf(mx, bf2f(v[j]));
    }
    u16* prow = &Pb[tid*104];
    float sum=0.f;
    #pragma unroll
    for(int c8=0;c8<10;c8++){
      u16x8 v = *(const u16x8*)(srp + c8*8);
      u16x8 o;
      #pragma unroll
      for(int j=0;j<8;j++){ float e=__expf(bf2f(v[j])-mx); sum+=e; o[j]=f2bf(e); }
      *(u16x8*)(prow + c8*8) = o;
    }
    #pragma unroll
    for(int j=80;j<96;j++) prow[j]=0;
    invr[tid] = 1.f/sum;
  }
  __syncthreads();
  for(int nh=0;nh<2;nh++){
    f32x4 Oa[2][8]={};
    for(int kt2=0;kt2<3;kt2++){
      for(int j=0;j<2;j++){
        int chunk=tid+j*256;
        int co=chunk>>2, ko2=(chunk&3)*8;
        g2l16(vT + ((size_t)(b*256+nh*128+co)*96 + kt2*32+ko2), &KVs[(size_t)chunk*8]);
      }
      __syncthreads();
      bf16x8 af[2], bfv[8];
      for(int mf=0;mf<2;mf++) af[mf]=ldfrag(&Pb[(w*32+mf*16+ln)*104 + kt2*32+qd*8]);
      for(int nf=0;nf<8;nf++) bfv[nf]=ldfrag(&KVs[(nf*16+ln)*32+qd*8]);
      for(int mf=0;mf<2;mf++) for(int nf=0;nf<8;nf++)
        Oa[mf][nf]=__builtin_amdgcn_mfma_f32_16x16x32_bf16(af[mf],bfv[nf],Oa[mf][nf],0,0,0);
      __syncthreads();
    }
    for(int mf=0;mf<2;mf++){
      #pragma unroll
      for(int r=0;r<4;r++){
        int ml=w*32+mf*16+qd*4+r;
        float inv = invr[ml];
        for(int nf=0;nf<8;nf++){
          int nl=nh*128+nf*16+ln;
          ob[((size_t)(b*HW_+p0+ml))*256+nl]=f2bf(Oa[mf][nf][r]*inv);
        }
      }
    }
  }
}

// ---------------- K8: out = x + (wo @ o^T) + bo, written NCHW ----------------
__global__ __launch_bounds__(256) void k_oproj(const u16* __restrict__ ob, const u16* __restrict__ woB,
    const float* __restrict__ bo, const float* __restrict__ x, float* __restrict__ outp){
  __shared__ u16 As[128*32];
  __shared__ u16 Bs[128*32];
  int bid=blockIdx.x;
  int b=bid>>6; int rr=bid&63; int cm=rr>>5, pt=rr&31;
  int c0=cm*128, p0=pt*128;
  int tid=threadIdx.x, w=tid>>6, lane=tid&63, ln=lane&15, qd=lane>>4, wm=w>>1, wn=w&1;
  int srow=tid>>2, koff=(tid&3)*8;
  f32x4 acc[4][4]={};
  for(int kt=0;kt<8;kt++){
    for(int j=0;j<2;j++){
      int m=srow+j*64;
      g2l16(woB + ((size_t)(c0+m)*256 + kt*32+koff),        &As[(size_t)tid*8+j*2048]);
      g2l16(ob  + ((size_t)(b*HW_+p0+m)*256 + kt*32+koff),  &Bs[(size_t)tid*8+j*2048]);
    }
    __syncthreads();
    bf16x8 af[4], bfv[4];
    for(int mf=0;mf<4;mf++) af[mf]=ldfrag(&As[(wm*64+mf*16+ln)*32+qd*8]);
    for(int nf=0;nf<4;nf++) bfv[nf]=ldfrag(&Bs[(wn*64+nf*16+ln)*32+qd*8]);
    for(int mf=0;mf<4;mf++) for(int nf=0;nf<4;nf++)
      acc[mf][nf]=__builtin_amdgcn_mfma_f32_16x16x32_bf16(af[mf],bfv[nf],acc[mf][nf],0,0,0);
    __syncthreads();
  }
  for(int mf=0;mf<4;mf++) for(int r=0;r<4;r++){
    int cl=c0+wm*64+mf*16+qd*4+r;
    float bias=bo[cl];
    for(int nf=0;nf<4;nf++){
      int pl=p0+wn*64+nf*16+ln;
      size_t idx=((size_t)(b*C_+cl))*HW_+pl;
      outp[idx]=x[idx]+acc[mf][nf][r]+bias;
    }
  }
}

extern "C" void kernel_launch(void* const* d_in, const int* in_sizes, int n_in,
                              void* d_out, int out_size, void* d_ws, size_t ws_size,
                              hipStream_t stream){
  const float* x      = (const float*)d_in[0];
  const float* ctx    = (const float*)d_in[1];
  const float* conv_w = (const float*)d_in[2];
  const float* conv_b = (const float*)d_in[3];
  const float* gnw    = (const float*)d_in[4];
  const float* gnb    = (const float*)d_in[5];
  const float* wq     = (const float*)d_in[6];
  const float* bq     = (const float*)d_in[7];
  const float* wk     = (const float*)d_in[8];
  const float* bk     = (const float*)d_in[9];
  const float* wv     = (const float*)d_in[10];
  const float* bv     = (const float*)d_in[11];
  const float* wo     = (const float*)d_in[12];
  const float* bo     = (const float*)d_in[13];
  char* ws = (char*)d_ws;
  u16* xpT  = (u16*)(ws + 0);            // 35,684,352 ; reused as q after conv
  u16* wBt  = (u16*)(ws + 35684352);     //  1,179,648
  u16* wqB  = (u16*)(ws + 36864000);     //    131,072
  u16* wkvB = (u16*)(ws + 36995072);     //    786,432
  u16* woB  = (u16*)(ws + 37781504);     //    131,072
  u16* ctxB = (u16*)(ws + 37912576);     //  1,892,352 (+74KB OOB read slack into hbuf)
  u16* hbuf = (u16*)(ws + 39804928);     // 33,554,432 (raw conv output)
  u16* kbv  = (u16*)(ws + 73359360);     //    630,784
  u16* vT   = (u16*)(ws + 73990144);     //    786,432
  u16* obuf = (u16*)(ws + 74776576);     // 33,554,432
  float* stats = (float*)(ws + 108331008); // 2048
  u16* qb = xpT;
  float* outp = (float*)d_out;

  k_prep  <<<9106, 256, 0, stream>>>(x, xpT, conv_w, wq, wo, wk, wv, ctx, wBt, wqB, woB, wkvB, ctxB, stats);
  k_conv  <<<512,  256, 0, stream>>>(xpT, wBt, conv_b, hbuf, stats);
  k_qgn   <<<512,  256, 0, stream>>>(hbuf, wqB, stats, gnw, gnb, bq, qb);
  k_kvproj<<<160,  256, 0, stream>>>(ctxB, wkvB, bk, bv, kbv, vT);
  k_attn  <<<512,  256, 0, stream>>>(qb, kbv, vT, obuf);
  k_oproj <<<1024, 256, 0, stream>>>(obuf, woB, bo, x, outp);
}